// Round 9
// baseline (592.371 us; speedup 1.0000x reference)
//
#include <hip/hip_runtime.h>

#define NBATCH  131072
#define THREADS 256            // 4 waves
#define BPB     16
#define NBLOCKS (NBATCH / BPB)     // 8192

typedef __attribute__((ext_vector_type(8))) _Float16 half8;
typedef __attribute__((ext_vector_type(4))) float f32x4;

// LDS (bytes):
//  [0, 19200):      sxT f16 [16 b][15 p][80B: 64B = ch 0..31 (21 data + 11 zero), 16B pad]
//                   conv0 writes y in place (same layout)
//  [19200, 20480):  lbuf f32 [16][20]  logit exchange
#define Y_RS 80
#define Y_BS 1200
#define LB_OFF 19200
#define SMEM_BYTES 20480

static __device__ __forceinline__ unsigned short f2h(float f) {
    return __builtin_bit_cast(unsigned short, (_Float16)f);   // RNE
}
static __device__ __forceinline__ unsigned int pack2h(float a, float b) {
    return (unsigned int)f2h(a) | ((unsigned int)f2h(b) << 16);
}
static __device__ __forceinline__ half8 splat8(float s) {
    const _Float16 h = (_Float16)s;
    half8 v;
    #pragma unroll
    for (int j = 0; j < 8; ++j) v[j] = h;
    return v;
}

// ---- conv0 via MFMA + attention softmax; h packed f16; y in-place to sxT ----
template<int P0, int NP>
__device__ __forceinline__ void conv0_att(char* sxT, float* lbuf,
        const half8 (&af0)[2],
        const float* __restrict__ attw, const float* __restrict__ attb,
        int col, int g, int lane) {
    half8 hq[NP];                      // packed h: {ch 4g..4g+3, 16+4g..19+4g}
    #pragma unroll
    for (int i = 0; i < NP; ++i) {
        const int p = P0 + i;
        half8 bf = *(const half8*)(sxT + col * Y_BS + p * Y_RS + g * 16);
        const f32x4 z = {0.f, 0.f, 0.f, 0.f};
        f32x4 h0 = __builtin_amdgcn_mfma_f32_16x16x32_f16(af0[0], bf, z, 0, 0, 0);
        f32x4 h1 = __builtin_amdgcn_mfma_f32_16x16x32_f16(af0[1], bf, z, 0, 0, 0);
        float4 a0 = *(const float4*)(attw + p * 32 + 4 * g);
        float4 a1 = *(const float4*)(attw + p * 32 + 16 + 4 * g);
        float lp = h0[0] * a0.x;
        lp = fmaf(h0[1], a0.y, lp); lp = fmaf(h0[2], a0.z, lp);
        lp = fmaf(h0[3], a0.w, lp); lp = fmaf(h1[0], a1.x, lp);
        lp = fmaf(h1[1], a1.y, lp); lp = fmaf(h1[2], a1.z, lp);
        lp = fmaf(h1[3], a1.w, lp);
        lp += __shfl_xor(lp, 16, 64);
        lp += __shfl_xor(lp, 32, 64);
        if (lane < 16) lbuf[col * 20 + p] = lp + attb[p];
        uint4 u;
        u.x = pack2h(h0[0], h0[1]); u.y = pack2h(h0[2], h0[3]);
        u.z = pack2h(h1[0], h1[1]); u.w = pack2h(h1[2], h1[3]);
        hq[i] = __builtin_bit_cast(half8, u);
    }
    __syncthreads();    // all 15 logits visible; all conv0 x-reads complete
    const float* lb = lbuf + col * 20;
    float4 l0 = *(const float4*)(lb + 0);
    float4 l1 = *(const float4*)(lb + 4);
    float4 l2 = *(const float4*)(lb + 8);
    float4 l3 = *(const float4*)(lb + 12);      // .w garbage, unused
    float lg[15] = {l0.x,l0.y,l0.z,l0.w, l1.x,l1.y,l1.z,l1.w,
                    l2.x,l2.y,l2.z,l2.w, l3.x,l3.y,l3.z};
    float mx = lg[0];
    #pragma unroll
    for (int l = 1; l < 15; ++l) mx = fmaxf(mx, lg[l]);
    float e[15], sum = 0.f;
    #pragma unroll
    for (int l = 0; l < 15; ++l) { e[l] = __expf(lg[l] - mx); sum += e[l]; }
    const float inv = 1.f / sum;
    #pragma unroll
    for (int i = 0; i < NP; ++i) {
        const int p = P0 + i;
        half8 ys = hq[i] * splat8(e[p] * inv);   // v_pk_mul_f16
        uint4 u = __builtin_bit_cast(uint4, ys);
        char* yr = sxT + col * Y_BS + p * Y_RS;
        uint2 u0; u0.x = u.x; u0.y = u.y;
        uint2 u1; u1.x = u.z; u1.y = u.w;
        *(uint2*)(yr + 8 * g) = u0;              // channels 4g..4g+3
        *(uint2*)(yr + 32 + 8 * g) = u1;         // channels 16+4g..19+4g
    }
}

// ---- conv1(+bn1+lrelu) -> reg fragments -> conv2(+bn2+lrelu) -> DIRECT global stores ----
// conv1 C-rows carry permuted channels chan1(mt,row)=32(mt>>1)+8(row>>2)+4(mt&1)+(row&3)
// so each lane's accumulators are exactly its conv2 B-fragment k-slices.
// Two sweeps (h = channel-half) keep af2 live-range at 24 VGPR.  Requires R0 == P0.
template<int R0, int NR, int NP>
__device__ __forceinline__ void stack23(
    const char* __restrict__ sxT, float* __restrict__ outb,
    const int col, const int g,
    const float* __restrict__ w1, const float* __restrict__ cb1,
    const float* __restrict__ g1, const float* __restrict__ bt1,
    const float* __restrict__ mn1, const float* __restrict__ vr1,
    const float* __restrict__ w2, const float* __restrict__ cb2,
    const float* __restrict__ g2, const float* __restrict__ bt2,
    const float* __restrict__ mn2, const float* __restrict__ vr2)
{
    half8 fr[NR][2];
    const char* yb = sxT + col * Y_BS;
    #pragma unroll
    for (int h = 0; h < 2; ++h) {
        // A-fragments for tiles 2h, 2h+1 (bn1 scale folded)
        half8 afA[3], afB[3];
        #pragma unroll
        for (int t = 0; t < 2; ++t) {
            const int o = 32*h + 8*(col>>2) + 4*t + (col&3);
            const float iva = g1[o] * rsqrtf(vr1[o] + 1e-5f);
            const float* wp = w1 + o*96 + g*24;
            float f[24];
            #pragma unroll
            for (int q = 0; q < 6; ++q) {
                float4 v = *(const float4*)(wp + 4*q);
                f[4*q+0]=v.x; f[4*q+1]=v.y; f[4*q+2]=v.z; f[4*q+3]=v.w;
            }
            #pragma unroll
            for (int s = 0; s < 3; ++s) {
                half8 fh;
                #pragma unroll
                for (int j = 0; j < 8; ++j) fh[j] = (_Float16)(f[j*3+s] * iva);
                if (t == 0) afA[s] = fh; else afB[s] = fh;
            }
        }
        float sh[8];
        #pragma unroll
        for (int t = 0; t < 2; ++t)
        #pragma unroll
        for (int r = 0; r < 4; ++r) {
            const int o = 32*h + 8*g + 4*t + r;
            const float iva = g1[o] * rsqrtf(vr1[o] + 1e-5f);
            sh[t*4+r] = bt1[o] + (cb1[o] - mn1[o]) * iva;
        }
        half8 y3[3];
        y3[(R0 + 0) % 3] = *(const half8*)(yb + (R0 + 0) * Y_RS + g * 16);
        y3[(R0 + 1) % 3] = *(const half8*)(yb + (R0 + 1) * Y_RS + g * 16);
        #pragma unroll
        for (int i = 0; i < NR; ++i) {
            const int r = R0 + i;
            y3[(r + 2) % 3] = *(const half8*)(yb + (r + 2) * Y_RS + g * 16);
            f32x4 a0 = {0.f,0.f,0.f,0.f}, a1 = {0.f,0.f,0.f,0.f};
            #pragma unroll
            for (int s = 0; s < 3; ++s) {
                const half8 yy = y3[(r + s) % 3];
                a0 = __builtin_amdgcn_mfma_f32_16x16x32_f16(afA[s], yy, a0, 0,0,0);
                a1 = __builtin_amdgcn_mfma_f32_16x16x32_f16(afB[s], yy, a1, 0,0,0);
            }
            float z0[4], z1[4];
            #pragma unroll
            for (int r2 = 0; r2 < 4; ++r2) {
                float t0 = a0[r2] + sh[r2];     z0[r2] = fmaxf(t0, 0.01f*t0);
                float t1 = a1[r2] + sh[4+r2];   z1[r2] = fmaxf(t1, 0.01f*t1);
            }
            uint4 u;
            u.x = pack2h(z0[0], z0[1]); u.y = pack2h(z0[2], z0[3]);
            u.z = pack2h(z1[0], z1[1]); u.w = pack2h(z1[2], z1[3]);
            fr[i][h] = __builtin_bit_cast(half8, u);
        }
    }

    // conv2 A-fragments (bn2 scale folded)
    half8 af3[2][6];
    #pragma unroll
    for (int mt = 0; mt < 2; ++mt) {
        const int o = mt * 16 + col;
        if (o < 20) {
            const float iva = g2[o] * rsqrtf(vr2[o] + 1e-5f);
            #pragma unroll
            for (int hh = 0; hh < 2; ++hh) {
                const float* wp = w2 + o*192 + hh*96 + g*24;
                float f[24];
                #pragma unroll
                for (int q = 0; q < 6; ++q) {
                    float4 v = *(const float4*)(wp + 4*q);
                    f[4*q+0]=v.x; f[4*q+1]=v.y; f[4*q+2]=v.z; f[4*q+3]=v.w;
                }
                #pragma unroll
                for (int tap = 0; tap < 3; ++tap) {
                    half8 fh;
                    #pragma unroll
                    for (int j = 0; j < 8; ++j) fh[j] = (_Float16)(f[j*3+tap] * iva);
                    af3[mt][tap*2 + hh] = fh;
                }
            }
        } else {
            #pragma unroll
            for (int s = 0; s < 6; ++s) {
                half8 zf;
                #pragma unroll
                for (int j = 0; j < 8; ++j) zf[j] = (_Float16)0.f;
                af3[mt][s] = zf;
            }
        }
    }
    float sha2v[8];
    #pragma unroll
    for (int mt = 0; mt < 2; ++mt)
    #pragma unroll
    for (int r = 0; r < 4; ++r) {
        const int o = mt*16 + 4*g + r;
        if (o < 20) {
            const float iva = g2[o] * rsqrtf(vr2[o] + 1e-5f);
            sha2v[mt*4+r] = bt2[o] + (cb2[o] - mn2[o]) * iva;
        } else sha2v[mt*4+r] = 0.f;
    }

    #pragma unroll
    for (int pp = 0; pp < NP; ++pp) {
        const int p = R0 + pp;                    // R0 == P0
        f32x4 acc0 = {0.f,0.f,0.f,0.f}, acc1 = {0.f,0.f,0.f,0.f};
        #pragma unroll
        for (int s = 0; s < 6; ++s) {
            const half8 bb = fr[pp + (s >> 1)][s & 1];
            acc0 = __builtin_amdgcn_mfma_f32_16x16x32_f16(af3[0][s], bb, acc0, 0,0,0);
            acc1 = __builtin_amdgcn_mfma_f32_16x16x32_f16(af3[1][s], bb, acc1, 0,0,0);
        }
        #pragma unroll
        for (int r = 0; r < 4; ++r) {
            float t0 = acc0[r] + sha2v[r];
            t0 = fmaxf(t0, 0.01f*t0);
            outb[(4*g + r)*11 + p] = t0;          // channels 0..15
        }
        if (g == 0) {
            #pragma unroll
            for (int r = 0; r < 4; ++r) {
                float t1 = acc1[r] + sha2v[4+r];
                t1 = fmaxf(t1, 0.01f*t1);
                outb[(16 + r)*11 + p] = t1;       // channels 16..19
            }
        }
    }
}

__global__ __launch_bounds__(THREADS, 3)
void peptide_v9(const float* __restrict__ x,
                const float* __restrict__ w0,     // [32][21]
                const float* __restrict__ attw,   // [15][32]
                const float* __restrict__ attb,   // [15]
                const float* __restrict__ w1,     // [64][32][3]
                const float* __restrict__ cb1,
                const float* __restrict__ g1, const float* __restrict__ bt1,
                const float* __restrict__ mn1, const float* __restrict__ vr1,
                const float* __restrict__ w2,     // [20][64][3]
                const float* __restrict__ cb2,
                const float* __restrict__ g2, const float* __restrict__ bt2,
                const float* __restrict__ mn2, const float* __restrict__ vr2,
                float* __restrict__ out)          // [B][20][11]
{
    __shared__ __align__(16) char smem[SMEM_BYTES];
    char*  sxT  = smem;
    float* lbuf = (float*)(smem + LB_OFF);

    const int tid  = threadIdx.x;
    const int lane = tid & 63;
    const int wv   = tid >> 6;      // 0..3
    const int col  = lane & 15;
    const int g    = lane >> 4;

    // ---- gather-transpose: global x [b][c][p] -> sxT f16 [b][p][c, zero-pad to 32] ----
    if (tid < 240) {
        const float* xg = x + (size_t)blockIdx.x * (BPB * 315);
        const int b = (int)(((unsigned)tid * 4370u) >> 16);   // tid / 15
        const int p = tid - b * 15;
        const float* src = xg + b * 315 + p;
        float v[21];
        #pragma unroll
        for (int c = 0; c < 21; ++c) v[c] = src[c * 15];
        uint4 d0, d1, d2, d3;
        d0.x = pack2h(v[0],  v[1]);  d0.y = pack2h(v[2],  v[3]);
        d0.z = pack2h(v[4],  v[5]);  d0.w = pack2h(v[6],  v[7]);
        d1.x = pack2h(v[8],  v[9]);  d1.y = pack2h(v[10], v[11]);
        d1.z = pack2h(v[12], v[13]); d1.w = pack2h(v[14], v[15]);
        d2.x = pack2h(v[16], v[17]); d2.y = pack2h(v[18], v[19]);
        d2.z = pack2h(v[20], 0.f);   d2.w = 0u;
        d3.x = 0u; d3.y = 0u; d3.z = 0u; d3.w = 0u;
        char* dst = sxT + b * Y_BS + p * Y_RS;
        *(uint4*)(dst)      = d0;
        *(uint4*)(dst + 16) = d1;
        *(uint4*)(dst + 32) = d2;
        *(uint4*)(dst + 48) = d3;
    }

    // conv0 A-fragments (rows = channels, k-pad zeroed)
    half8 af0[2];
    #pragma unroll
    for (int mt = 0; mt < 2; ++mt) {
        const int o = mt * 16 + col;
        #pragma unroll
        for (int j = 0; j < 8; ++j) {
            const int c = 8 * g + j;
            af0[mt][j] = (c < 21) ? (_Float16)w0[o * 21 + c] : (_Float16)0.f;
        }
    }
    __syncthreads();                      // xT ready

    // ---- conv0 MFMA + attention softmax (y in-place); p split 4/4/4/3 ----
    if      (wv == 0) conv0_att<0,  4>(sxT, lbuf, af0, attw, attb, col, g, lane);
    else if (wv == 1) conv0_att<4,  4>(sxT, lbuf, af0, attw, attb, col, g, lane);
    else if (wv == 2) conv0_att<8,  4>(sxT, lbuf, af0, attw, attb, col, g, lane);
    else              conv0_att<12, 3>(sxT, lbuf, af0, attw, attb, col, g, lane);
    __syncthreads();                      // y complete (cross-wave rows)

    // ---- conv1 -> regs -> conv2 -> direct global stores; p split 3/3/3/2 ----
    float* outb = out + ((size_t)blockIdx.x * BPB + col) * 220;
    if      (wv == 0) stack23<0, 5, 3>(sxT, outb, col, g, w1, cb1, g1, bt1, mn1, vr1,
                                       w2, cb2, g2, bt2, mn2, vr2);
    else if (wv == 1) stack23<3, 5, 3>(sxT, outb, col, g, w1, cb1, g1, bt1, mn1, vr1,
                                       w2, cb2, g2, bt2, mn2, vr2);
    else if (wv == 2) stack23<6, 5, 3>(sxT, outb, col, g, w1, cb1, g1, bt1, mn1, vr1,
                                       w2, cb2, g2, bt2, mn2, vr2);
    else              stack23<9, 4, 2>(sxT, outb, col, g, w1, cb1, g1, bt1, mn1, vr1,
                                       w2, cb2, g2, bt2, mn2, vr2);
}

extern "C" void kernel_launch(void* const* d_in, const int* in_sizes, int n_in,
                              void* d_out, int out_size, void* d_ws, size_t ws_size,
                              hipStream_t stream) {
    const float* x    = (const float*)d_in[0];
    const float* w0   = (const float*)d_in[1];
    const float* attw = (const float*)d_in[2];
    const float* attb = (const float*)d_in[3];
    const float* w1   = (const float*)d_in[4];
    const float* cb1  = (const float*)d_in[5];
    const float* g1   = (const float*)d_in[6];
    const float* bt1  = (const float*)d_in[7];
    const float* mn1  = (const float*)d_in[8];
    const float* vr1  = (const float*)d_in[9];
    const float* w2   = (const float*)d_in[10];
    const float* cb2  = (const float*)d_in[11];
    const float* g2   = (const float*)d_in[12];
    const float* bt2  = (const float*)d_in[13];
    const float* mn2  = (const float*)d_in[14];
    const float* vr2  = (const float*)d_in[15];

    dim3 grid(NBLOCKS);
    dim3 block(THREADS);
    hipLaunchKernelGGL(peptide_v9, grid, block, 0, stream,
                       x, w0, attw, attb,
                       w1, cb1, g1, bt1, mn1, vr1,
                       w2, cb2, g2, bt2, mn2, vr2,
                       (float*)d_out);
}

// Round 10
// 159.311 us; speedup vs baseline: 3.7183x; 3.7183x over previous
//
#include <hip/hip_runtime.h>

#define NBATCH  131072
#define THREADS 128
#define BPB     16
#define NBLOCKS (NBATCH / BPB)     // 8192

typedef __attribute__((ext_vector_type(8))) _Float16 half8;
typedef __attribute__((ext_vector_type(4))) float f32x4;

// LDS (bytes):
//  [0, 19200):      sxT f16 [16 b][15 p][80B: 64B = ch 0..31 (21 data + 11 zero), 16B pad]
//                   conv0 writes y in place; stage3 reuses [0,14080) as out f32 [16][220]
//  [19200, 20480):  lbuf f32 [16][20]  logit exchange
#define Y_RS 80
#define Y_BS 1200
#define LB_OFF 19200
#define SMEM_BYTES 20480
#define OUT_SDW 220

static __device__ __forceinline__ unsigned short f2h(float f) {
    return __builtin_bit_cast(unsigned short, (_Float16)f);   // RNE
}
static __device__ __forceinline__ unsigned int pack2h(float a, float b) {
    return (unsigned int)f2h(a) | ((unsigned int)f2h(b) << 16);
}
static __device__ __forceinline__ half8 splat8(float s) {
    const _Float16 h = (_Float16)s;
    half8 v;
    #pragma unroll
    for (int j = 0; j < 8; ++j) v[j] = h;
    return v;
}

// ---- conv0 via MFMA + attention softmax; h packed f16; y in-place to sxT ----
template<int P0, int NP>
__device__ __forceinline__ void conv0_att(char* sxT, float* lbuf,
        const half8 (&af0)[2],
        const float* __restrict__ attw, const float* __restrict__ attb,
        int col, int g, int lane) {
    half8 hq[NP];                      // packed h: {ch 4g..4g+3, 16+4g..19+4g}
    #pragma unroll
    for (int i = 0; i < NP; ++i) {
        const int p = P0 + i;
        half8 bf = *(const half8*)(sxT + col * Y_BS + p * Y_RS + g * 16);
        const f32x4 z = {0.f, 0.f, 0.f, 0.f};
        f32x4 h0 = __builtin_amdgcn_mfma_f32_16x16x32_f16(af0[0], bf, z, 0, 0, 0);
        f32x4 h1 = __builtin_amdgcn_mfma_f32_16x16x32_f16(af0[1], bf, z, 0, 0, 0);
        float4 a0 = *(const float4*)(attw + p * 32 + 4 * g);
        float4 a1 = *(const float4*)(attw + p * 32 + 16 + 4 * g);
        float lp = h0[0] * a0.x;
        lp = fmaf(h0[1], a0.y, lp); lp = fmaf(h0[2], a0.z, lp);
        lp = fmaf(h0[3], a0.w, lp); lp = fmaf(h1[0], a1.x, lp);
        lp = fmaf(h1[1], a1.y, lp); lp = fmaf(h1[2], a1.z, lp);
        lp = fmaf(h1[3], a1.w, lp);
        lp += __shfl_xor(lp, 16, 64);
        lp += __shfl_xor(lp, 32, 64);
        if (lane < 16) lbuf[col * 20 + p] = lp + attb[p];
        uint4 u;
        u.x = pack2h(h0[0], h0[1]); u.y = pack2h(h0[2], h0[3]);
        u.z = pack2h(h1[0], h1[1]); u.w = pack2h(h1[2], h1[3]);
        hq[i] = __builtin_bit_cast(half8, u);
    }
    __syncthreads();    // all 15 logits visible; all conv0 x-reads complete
    const float* lb = lbuf + col * 20;
    float4 l0 = *(const float4*)(lb + 0);
    float4 l1 = *(const float4*)(lb + 4);
    float4 l2 = *(const float4*)(lb + 8);
    float4 l3 = *(const float4*)(lb + 12);      // .w garbage, unused
    float lg[15] = {l0.x,l0.y,l0.z,l0.w, l1.x,l1.y,l1.z,l1.w,
                    l2.x,l2.y,l2.z,l2.w, l3.x,l3.y,l3.z};
    float mx = lg[0];
    #pragma unroll
    for (int l = 1; l < 15; ++l) mx = fmaxf(mx, lg[l]);
    float e[15], sum = 0.f;
    #pragma unroll
    for (int l = 0; l < 15; ++l) { e[l] = __expf(lg[l] - mx); sum += e[l]; }
    const float inv = 1.f / sum;
    #pragma unroll
    for (int i = 0; i < NP; ++i) {
        const int p = P0 + i;
        half8 ys = hq[i] * splat8(e[p] * inv);   // v_pk_mul_f16
        uint4 u = __builtin_bit_cast(uint4, ys);
        char* yr = sxT + col * Y_BS + p * Y_RS;
        uint2 u0; u0.x = u.x; u0.y = u.y;
        uint2 u1; u1.x = u.z; u1.y = u.w;
        *(uint2*)(yr + 8 * g) = u0;              // channels 4g..4g+3
        *(uint2*)(yr + 32 + 8 * g) = u1;         // channels 16+4g..19+4g
    }
}

// ---- conv1 half-sweep H: channels 32H..32H+31 -> frH (register B-fragments) ----
// C-rows carry permuted channels chan1 = 32H + 8*(row>>2) + 4t + (row&3), so each
// lane's accumulators are exactly its conv2 B-fragment k-slices for half H.
template<int H, int R0, int NR>
__device__ __forceinline__ void conv1_half(
    const char* __restrict__ yb, half8 (&frH)[NR],
    const int col, const int g,
    const float* __restrict__ w1, const float* __restrict__ cb1,
    const float* __restrict__ g1, const float* __restrict__ bt1,
    const float* __restrict__ mn1, const float* __restrict__ vr1)
{
    half8 afA[3], afB[3];
    #pragma unroll
    for (int t = 0; t < 2; ++t) {
        const int o = 32*H + 8*(col>>2) + 4*t + (col&3);
        const float iva = g1[o] * rsqrtf(vr1[o] + 1e-5f);
        const float* wp = w1 + o*96 + g*24;
        float f[24];
        #pragma unroll
        for (int q = 0; q < 6; ++q) {
            float4 v = *(const float4*)(wp + 4*q);
            f[4*q+0]=v.x; f[4*q+1]=v.y; f[4*q+2]=v.z; f[4*q+3]=v.w;
        }
        #pragma unroll
        for (int s = 0; s < 3; ++s) {
            half8 fh;
            #pragma unroll
            for (int j = 0; j < 8; ++j) fh[j] = (_Float16)(f[j*3+s] * iva);
            if (t == 0) afA[s] = fh; else afB[s] = fh;
        }
    }
    float sh[8];
    #pragma unroll
    for (int t = 0; t < 2; ++t)
    #pragma unroll
    for (int r = 0; r < 4; ++r) {
        const int o = 32*H + 8*g + 4*t + r;
        const float iva = g1[o] * rsqrtf(vr1[o] + 1e-5f);
        sh[t*4+r] = bt1[o] + (cb1[o] - mn1[o]) * iva;
    }
    half8 y3[3];
    y3[(R0 + 0) % 3] = *(const half8*)(yb + (R0 + 0) * Y_RS + g * 16);
    y3[(R0 + 1) % 3] = *(const half8*)(yb + (R0 + 1) * Y_RS + g * 16);
    #pragma unroll
    for (int i = 0; i < NR; ++i) {
        const int r = R0 + i;
        y3[(r + 2) % 3] = *(const half8*)(yb + (r + 2) * Y_RS + g * 16);
        f32x4 a0 = {0.f,0.f,0.f,0.f}, a1 = {0.f,0.f,0.f,0.f};
        #pragma unroll
        for (int s = 0; s < 3; ++s) {
            const half8 yy = y3[(r + s) % 3];
            a0 = __builtin_amdgcn_mfma_f32_16x16x32_f16(afA[s], yy, a0, 0,0,0);
            a1 = __builtin_amdgcn_mfma_f32_16x16x32_f16(afB[s], yy, a1, 0,0,0);
        }
        float z0[4], z1[4];
        #pragma unroll
        for (int r2 = 0; r2 < 4; ++r2) {
            float t0 = a0[r2] + sh[r2];     z0[r2] = fmaxf(t0, 0.01f*t0);
            float t1 = a1[r2] + sh[4+r2];   z1[r2] = fmaxf(t1, 0.01f*t1);
        }
        uint4 u;
        u.x = pack2h(z0[0], z0[1]); u.y = pack2h(z0[2], z0[3]);
        u.z = pack2h(z1[0], z1[1]); u.w = pack2h(z1[2], z1[3]);
        frH[i] = __builtin_bit_cast(half8, u);
    }
}

// ---- conv2 tile MT (output channels MT*16 + row) from register fragments -> LDS staging ----
template<int MT, int P0, int NP, int NR>
__device__ __forceinline__ void conv2_tile(
    float* __restrict__ sout, const half8 (&fr0)[NR], const half8 (&fr1)[NR],
    const int col, const int g,
    const float* __restrict__ w2, const float* __restrict__ cb2,
    const float* __restrict__ g2, const float* __restrict__ bt2,
    const float* __restrict__ mn2, const float* __restrict__ vr2)
{
    const int o = MT*16 + col;
    half8 af3[6];
    if (o < 20) {
        const float iva = g2[o] * rsqrtf(vr2[o] + 1e-5f);
        #pragma unroll
        for (int hh = 0; hh < 2; ++hh) {
            const float* wp = w2 + o*192 + hh*96 + g*24;
            float f[24];
            #pragma unroll
            for (int q = 0; q < 6; ++q) {
                float4 v = *(const float4*)(wp + 4*q);
                f[4*q+0]=v.x; f[4*q+1]=v.y; f[4*q+2]=v.z; f[4*q+3]=v.w;
            }
            #pragma unroll
            for (int tap = 0; tap < 3; ++tap) {
                half8 fh;
                #pragma unroll
                for (int j = 0; j < 8; ++j) fh[j] = (_Float16)(f[j*3+tap] * iva);
                af3[tap*2 + hh] = fh;
            }
        }
    } else {
        #pragma unroll
        for (int s = 0; s < 6; ++s) {
            half8 zf;
            #pragma unroll
            for (int j = 0; j < 8; ++j) zf[j] = (_Float16)0.f;
            af3[s] = zf;
        }
    }
    float sh2[4];
    #pragma unroll
    for (int r = 0; r < 4; ++r) {
        const int oc = MT*16 + 4*g + r;
        if (oc < 20) {
            const float iva = g2[oc] * rsqrtf(vr2[oc] + 1e-5f);
            sh2[r] = bt2[oc] + (cb2[oc] - mn2[oc]) * iva;
        } else sh2[r] = 0.f;
    }
    #pragma unroll
    for (int pp = 0; pp < NP; ++pp) {
        const int p = P0 + pp;
        f32x4 acc = {0.f,0.f,0.f,0.f};
        #pragma unroll
        for (int s = 0; s < 6; ++s) {
            const half8 bb = (s & 1) ? fr1[pp + (s >> 1)] : fr0[pp + (s >> 1)];
            acc = __builtin_amdgcn_mfma_f32_16x16x32_f16(af3[s], bb, acc, 0,0,0);
        }
        #pragma unroll
        for (int r = 0; r < 4; ++r) {
            const int oc = MT*16 + 4*g + r;
            if (oc < 20) {
                float t0 = acc[r] + sh2[r];
                t0 = fmaxf(t0, 0.01f*t0);
                sout[col*OUT_SDW + oc*11 + p] = t0;
            }
        }
    }
}

// ---- conv1 (two half-sweeps) -> fr regs -> conv2 (two tile-sweeps) -> LDS staging ----
template<int R0, int NR, int P0, int NP>
__device__ __forceinline__ void stack23(
    char* __restrict__ sxT, const int col, const int g,
    const float* __restrict__ w1, const float* __restrict__ cb1,
    const float* __restrict__ g1, const float* __restrict__ bt1,
    const float* __restrict__ mn1, const float* __restrict__ vr1,
    const float* __restrict__ w2, const float* __restrict__ cb2,
    const float* __restrict__ g2, const float* __restrict__ bt2,
    const float* __restrict__ mn2, const float* __restrict__ vr2)
{
    float* sout = (float*)sxT;
    const char* yb = sxT + col * Y_BS;
    half8 fr0[NR], fr1[NR];
    conv1_half<0, R0, NR>(yb, fr0, col, g, w1, cb1, g1, bt1, mn1, vr1);
    __builtin_amdgcn_sched_barrier(0);    // keep the two halves' af live-ranges separate
    conv1_half<1, R0, NR>(yb, fr1, col, g, w1, cb1, g1, bt1, mn1, vr1);
    __syncthreads();   // all y reads done before out staging overwrites sxT
    conv2_tile<0, P0, NP, NR>(sout, fr0, fr1, col, g, w2, cb2, g2, bt2, mn2, vr2);
    __builtin_amdgcn_sched_barrier(0);
    conv2_tile<1, P0, NP, NR>(sout, fr0, fr1, col, g, w2, cb2, g2, bt2, mn2, vr2);
}

__global__ __launch_bounds__(THREADS, 2)
void peptide_v10(const float* __restrict__ x,
                 const float* __restrict__ w0,     // [32][21]
                 const float* __restrict__ attw,   // [15][32]
                 const float* __restrict__ attb,   // [15]
                 const float* __restrict__ w1,     // [64][32][3]
                 const float* __restrict__ cb1,
                 const float* __restrict__ g1, const float* __restrict__ bt1,
                 const float* __restrict__ mn1, const float* __restrict__ vr1,
                 const float* __restrict__ w2,     // [20][64][3]
                 const float* __restrict__ cb2,
                 const float* __restrict__ g2, const float* __restrict__ bt2,
                 const float* __restrict__ mn2, const float* __restrict__ vr2,
                 float* __restrict__ out)          // [B][20][11]
{
    __shared__ __align__(16) char smem[SMEM_BYTES];
    char*  sxT  = smem;
    float* lbuf = (float*)(smem + LB_OFF);

    const int tid  = threadIdx.x;
    const int lane = tid & 63;
    const int wv   = tid >> 6;
    const int col  = lane & 15;
    const int g    = lane >> 4;

    // ---- gather-transpose: global x [b][c][p] -> sxT f16 [b][p][c, zero-pad to 32] ----
    {
        const float* xg = x + (size_t)blockIdx.x * (BPB * 315);
        #pragma unroll
        for (int q = 0; q < 2; ++q) {
            const int u = q * THREADS + tid;          // (b,p) task
            if (u < 240) {
                const int b = (int)(((unsigned)u * 4370u) >> 16);   // u / 15
                const int p = u - b * 15;
                const float* src = xg + b * 315 + p;
                float v[21];
                #pragma unroll
                for (int c = 0; c < 21; ++c) v[c] = src[c * 15];
                uint4 d0, d1, d2, d3;
                d0.x = pack2h(v[0],  v[1]);  d0.y = pack2h(v[2],  v[3]);
                d0.z = pack2h(v[4],  v[5]);  d0.w = pack2h(v[6],  v[7]);
                d1.x = pack2h(v[8],  v[9]);  d1.y = pack2h(v[10], v[11]);
                d1.z = pack2h(v[12], v[13]); d1.w = pack2h(v[14], v[15]);
                d2.x = pack2h(v[16], v[17]); d2.y = pack2h(v[18], v[19]);
                d2.z = pack2h(v[20], 0.f);   d2.w = 0u;
                d3.x = 0u; d3.y = 0u; d3.z = 0u; d3.w = 0u;
                char* dst = sxT + b * Y_BS + p * Y_RS;
                *(uint4*)(dst)      = d0;
                *(uint4*)(dst + 16) = d1;
                *(uint4*)(dst + 32) = d2;
                *(uint4*)(dst + 48) = d3;
            }
        }
    }

    // conv0 A-fragments (rows = channels, k-pad zeroed)
    half8 af0[2];
    #pragma unroll
    for (int mt = 0; mt < 2; ++mt) {
        const int o = mt * 16 + col;
        #pragma unroll
        for (int j = 0; j < 8; ++j) {
            const int c = 8 * g + j;
            af0[mt][j] = (c < 21) ? (_Float16)w0[o * 21 + c] : (_Float16)0.f;
        }
    }
    __syncthreads();                      // xT ready

    // ---- conv0 MFMA + attention softmax (y in-place) ----
    if (wv == 0) conv0_att<0, 8>(sxT, lbuf, af0, attw, attb, col, g, lane);
    else         conv0_att<8, 7>(sxT, lbuf, af0, attw, attb, col, g, lane);
    __syncthreads();                      // y complete (cross-wave rows)

    // ---- conv1 -> regs -> conv2 -> out staging ----
    if (wv == 0) stack23<0, 8, 0, 6>(sxT, col, g, w1, cb1, g1, bt1, mn1, vr1,
                                     w2, cb2, g2, bt2, mn2, vr2);
    else         stack23<6, 7, 6, 5>(sxT, col, g, w1, cb1, g1, bt1, mn1, vr1,
                                     w2, cb2, g2, bt2, mn2, vr2);
    __syncthreads();                      // out staging complete

    // ---- gap-free coalesced copy-out: 16 x 220 dw = one 14080 B span ----
    {
        float* ob = out + (size_t)blockIdx.x * (BPB * 220);
        const float* sf = (const float*)sxT;
        #pragma unroll
        for (int j = 0; j < 7; ++j) {
            const int u = j * THREADS + tid;          // 16B unit
            if (u < 880) {
                f32x4 v = *(const f32x4*)(sf + u * 4);
                *(f32x4*)(ob + u * 4) = v;
            }
        }
    }
}

extern "C" void kernel_launch(void* const* d_in, const int* in_sizes, int n_in,
                              void* d_out, int out_size, void* d_ws, size_t ws_size,
                              hipStream_t stream) {
    const float* x    = (const float*)d_in[0];
    const float* w0   = (const float*)d_in[1];
    const float* attw = (const float*)d_in[2];
    const float* attb = (const float*)d_in[3];
    const float* w1   = (const float*)d_in[4];
    const float* cb1  = (const float*)d_in[5];
    const float* g1   = (const float*)d_in[6];
    const float* bt1  = (const float*)d_in[7];
    const float* mn1  = (const float*)d_in[8];
    const float* vr1  = (const float*)d_in[9];
    const float* w2   = (const float*)d_in[10];
    const float* cb2  = (const float*)d_in[11];
    const float* g2   = (const float*)d_in[12];
    const float* bt2  = (const float*)d_in[13];
    const float* mn2  = (const float*)d_in[14];
    const float* vr2  = (const float*)d_in[15];

    dim3 grid(NBLOCKS);
    dim3 block(THREADS);
    hipLaunchKernelGGL(peptide_v10, grid, block, 0, stream,
                       x, w0, attw, attb,
                       w1, cb1, g1, bt1, mn1, vr1,
                       w2, cb2, g2, bt2, mn2, vr2,
                       (float*)d_out);
}

// Round 11
// 102.163 us; speedup vs baseline: 5.7983x; 1.5594x over previous
//
#include <hip/hip_runtime.h>

#define NBATCH  131072
#define THREADS 128
#define BPB     16
#define NBLOCKS (NBATCH / BPB)     // 8192

typedef __attribute__((ext_vector_type(8))) _Float16 half8;
typedef __attribute__((ext_vector_type(4))) float f32x4;

// LDS (bytes): sxT f16 [16 b][15 p][80B: 64B = ch 0..31 (21 data + 11 zero), 12B pad, 4B logit]
//              conv0 writes y in place; stage3 reuses [0,14080) as out f32 [16][220]
#define Y_RS 80
#define Y_BS 1200
#define SMEM_BYTES 19200
#define OUT_SDW 220

// d_ws layout (bytes):
//  [0,     2048):  wf0 uint4 [2 mt][64 lane]            conv0 A-fragments
//  [2048, 14336):  wf1 uint4 [2 H][2 t][3 s][64 lane]   conv1 A-fragments (bn1 folded)
//  [14336,26624):  wf2 uint4 [2 MT][2 hh][3 tap][64]    conv2 A-fragments (bn2 folded, o>=20 zero)
//  [26624,26880):  sh1 f32 [4 g][16]                    conv1 shifts
//  [26880,27008):  sh2 f32 [4 g][8]                     conv2 shifts
#define WF1_OFF 2048
#define WF2_OFF 14336
#define SH1_OFF 26624
#define SH2_OFF 26880

static __device__ __forceinline__ unsigned short f2h(float f) {
    return __builtin_bit_cast(unsigned short, (_Float16)f);   // RNE
}
static __device__ __forceinline__ unsigned int pack2h(float a, float b) {
    return (unsigned int)f2h(a) | ((unsigned int)f2h(b) << 16);
}
static __device__ __forceinline__ half8 splat8(float s) {
    const _Float16 h = (_Float16)s;
    half8 v;
    #pragma unroll
    for (int j = 0; j < 8; ++j) v[j] = h;
    return v;
}

// ================= prep kernel: fold BN, pack per-lane fragments into d_ws ==============
__global__ __launch_bounds__(64, 1)
void peptide_prep(const float* __restrict__ w0,
                  const float* __restrict__ w1, const float* __restrict__ cb1,
                  const float* __restrict__ g1, const float* __restrict__ bt1,
                  const float* __restrict__ mn1, const float* __restrict__ vr1,
                  const float* __restrict__ w2, const float* __restrict__ cb2,
                  const float* __restrict__ g2, const float* __restrict__ bt2,
                  const float* __restrict__ mn2, const float* __restrict__ vr2,
                  char* __restrict__ ws)
{
    const int lane = threadIdx.x;
    const int col = lane & 15, g = lane >> 4;
    uint4* wf0 = (uint4*)ws;
    uint4* wf1 = (uint4*)(ws + WF1_OFF);
    uint4* wf2 = (uint4*)(ws + WF2_OFF);
    float* sh1 = (float*)(ws + SH1_OFF);
    float* sh2 = (float*)(ws + SH2_OFF);

    // conv0 fragments
    #pragma unroll
    for (int mt = 0; mt < 2; ++mt) {
        const int o = mt * 16 + col;
        half8 fh;
        #pragma unroll
        for (int j = 0; j < 8; ++j) {
            const int c = 8 * g + j;
            fh[j] = (c < 21) ? (_Float16)w0[o * 21 + c] : (_Float16)0.f;
        }
        wf0[mt * 64 + lane] = __builtin_bit_cast(uint4, fh);
    }
    // conv1 fragments, bn1 scale folded; permuted channel o = 32H + 8(col>>2) + 4t + (col&3)
    #pragma unroll
    for (int H = 0; H < 2; ++H)
    #pragma unroll
    for (int t = 0; t < 2; ++t) {
        const int o = 32*H + 8*(col>>2) + 4*t + (col&3);
        const float iva = g1[o] * rsqrtf(vr1[o] + 1e-5f);
        #pragma unroll
        for (int s = 0; s < 3; ++s) {
            half8 fh;
            #pragma unroll
            for (int j = 0; j < 8; ++j)
                fh[j] = (_Float16)(w1[o*96 + g*24 + j*3 + s] * iva);
            wf1[((H*2 + t)*3 + s)*64 + lane] = __builtin_bit_cast(uint4, fh);
        }
    }
    // conv2 fragments, bn2 folded, zero for o >= 20
    #pragma unroll
    for (int MT = 0; MT < 2; ++MT) {
        const int o = MT * 16 + col;
        const float iva = (o < 20) ? g2[o] * rsqrtf(vr2[o] + 1e-5f) : 0.f;
        #pragma unroll
        for (int hh = 0; hh < 2; ++hh)
        #pragma unroll
        for (int tap = 0; tap < 3; ++tap) {
            half8 fh;
            #pragma unroll
            for (int j = 0; j < 8; ++j)
                fh[j] = (o < 20) ? (_Float16)(w2[o*192 + hh*96 + g*24 + j*3 + tap] * iva)
                                 : (_Float16)0.f;
            wf2[((MT*2 + hh)*3 + tap)*64 + lane] = __builtin_bit_cast(uint4, fh);
        }
    }
    // shift vectors (per g)
    if (col == 0) {
        #pragma unroll
        for (int k = 0; k < 16; ++k) {
            const int H = k >> 3, t = (k >> 2) & 1, r = k & 3;
            const int o = 32*H + 8*g + 4*t + r;
            const float iva = g1[o] * rsqrtf(vr1[o] + 1e-5f);
            sh1[g*16 + k] = bt1[o] + (cb1[o] - mn1[o]) * iva;
        }
        #pragma unroll
        for (int k = 0; k < 8; ++k) {
            const int MT = k >> 2, r = k & 3;
            const int oc = MT*16 + 4*g + r;
            if (oc < 20) {
                const float iva = g2[oc] * rsqrtf(vr2[oc] + 1e-5f);
                sh2[g*8 + k] = bt2[oc] + (cb2[oc] - mn2[oc]) * iva;
            } else sh2[g*8 + k] = 0.f;
        }
    }
}

// ---- conv0 via MFMA + attention softmax; h packed f16; y in-place; logits in row pads ----
template<int P0, int NP>
__device__ __forceinline__ void conv0_att(char* sxT,
        const half8 (&af0)[2],
        const float* __restrict__ attw, const float* __restrict__ attb,
        int col, int g, int lane) {
    half8 hq[NP];                      // packed h: {ch 4g..4g+3, 16+4g..19+4g}
    #pragma unroll
    for (int i = 0; i < NP; ++i) {
        const int p = P0 + i;
        half8 bf = *(const half8*)(sxT + col * Y_BS + p * Y_RS + g * 16);
        const f32x4 z = {0.f, 0.f, 0.f, 0.f};
        f32x4 h0 = __builtin_amdgcn_mfma_f32_16x16x32_f16(af0[0], bf, z, 0, 0, 0);
        f32x4 h1 = __builtin_amdgcn_mfma_f32_16x16x32_f16(af0[1], bf, z, 0, 0, 0);
        float4 a0 = *(const float4*)(attw + p * 32 + 4 * g);
        float4 a1 = *(const float4*)(attw + p * 32 + 16 + 4 * g);
        float lp = h0[0] * a0.x;
        lp = fmaf(h0[1], a0.y, lp); lp = fmaf(h0[2], a0.z, lp);
        lp = fmaf(h0[3], a0.w, lp); lp = fmaf(h1[0], a1.x, lp);
        lp = fmaf(h1[1], a1.y, lp); lp = fmaf(h1[2], a1.z, lp);
        lp = fmaf(h1[3], a1.w, lp);
        lp += __shfl_xor(lp, 16, 64);
        lp += __shfl_xor(lp, 32, 64);
        if (lane < 16) *(float*)(sxT + lane * Y_BS + p * Y_RS + 64) = lp + attb[p];
        uint4 u;
        u.x = pack2h(h0[0], h0[1]); u.y = pack2h(h0[2], h0[3]);
        u.z = pack2h(h1[0], h1[1]); u.w = pack2h(h1[2], h1[3]);
        hq[i] = __builtin_bit_cast(half8, u);
    }
    __syncthreads();    // all 15 logits visible; all conv0 x-reads complete
    float lg[15];
    #pragma unroll
    for (int l = 0; l < 15; ++l)
        lg[l] = *(const float*)(sxT + col * Y_BS + l * Y_RS + 64);
    // tree max / sum (depth 4 instead of serial 14)
    float mA = fmaxf(fmaxf(fmaxf(lg[0],lg[1]), fmaxf(lg[2],lg[3])),
                     fmaxf(fmaxf(lg[4],lg[5]), fmaxf(lg[6],lg[7])));
    float mB = fmaxf(fmaxf(fmaxf(lg[8],lg[9]), fmaxf(lg[10],lg[11])),
                     fmaxf(fmaxf(lg[12],lg[13]), lg[14]));
    const float mx = fmaxf(mA, mB);
    float e[15];
    #pragma unroll
    for (int l = 0; l < 15; ++l) e[l] = __expf(lg[l] - mx);
    float sA = ((e[0]+e[1]) + (e[2]+e[3])) + ((e[4]+e[5]) + (e[6]+e[7]));
    float sB = ((e[8]+e[9]) + (e[10]+e[11])) + ((e[12]+e[13]) + e[14]);
    const float inv = 1.f / (sA + sB);
    #pragma unroll
    for (int i = 0; i < NP; ++i) {
        const int p = P0 + i;
        half8 ys = hq[i] * splat8(e[p] * inv);   // v_pk_mul_f16
        uint4 u = __builtin_bit_cast(uint4, ys);
        char* yr = sxT + col * Y_BS + p * Y_RS;
        uint2 u0; u0.x = u.x; u0.y = u.y;
        uint2 u1; u1.x = u.z; u1.y = u.w;
        *(uint2*)(yr + 8 * g) = u0;              // channels 4g..4g+3
        *(uint2*)(yr + 32 + 8 * g) = u1;         // channels 16+4g..19+4g
    }
}

// ---- conv1 half-sweep H from prefolded fragments -> frH register B-fragments ----
template<int H, int R0, int NR>
__device__ __forceinline__ void conv1_half(
    const char* __restrict__ yb, half8 (&frH)[NR],
    const int lane, const int g, const char* __restrict__ ws)
{
    const uint4* wf1 = (const uint4*)(ws + WF1_OFF);
    half8 afA[3], afB[3];
    #pragma unroll
    for (int s = 0; s < 3; ++s) {
        afA[s] = __builtin_bit_cast(half8, wf1[((H*2 + 0)*3 + s)*64 + lane]);
        afB[s] = __builtin_bit_cast(half8, wf1[((H*2 + 1)*3 + s)*64 + lane]);
    }
    const float* sh1 = (const float*)(ws + SH1_OFF) + g*16 + H*8;
    float4 shv0 = *(const float4*)(sh1);
    float4 shv1 = *(const float4*)(sh1 + 4);
    const float sh[8] = {shv0.x, shv0.y, shv0.z, shv0.w, shv1.x, shv1.y, shv1.z, shv1.w};

    half8 y3[3];
    y3[(R0 + 0) % 3] = *(const half8*)(yb + (R0 + 0) * Y_RS + g * 16);
    y3[(R0 + 1) % 3] = *(const half8*)(yb + (R0 + 1) * Y_RS + g * 16);
    #pragma unroll
    for (int i = 0; i < NR; ++i) {
        const int r = R0 + i;
        y3[(r + 2) % 3] = *(const half8*)(yb + (r + 2) * Y_RS + g * 16);
        f32x4 a0 = {0.f,0.f,0.f,0.f}, a1 = {0.f,0.f,0.f,0.f};
        #pragma unroll
        for (int s = 0; s < 3; ++s) {
            const half8 yy = y3[(r + s) % 3];
            a0 = __builtin_amdgcn_mfma_f32_16x16x32_f16(afA[s], yy, a0, 0,0,0);
            a1 = __builtin_amdgcn_mfma_f32_16x16x32_f16(afB[s], yy, a1, 0,0,0);
        }
        float z0[4], z1[4];
        #pragma unroll
        for (int r2 = 0; r2 < 4; ++r2) {
            float t0 = a0[r2] + sh[r2];     z0[r2] = fmaxf(t0, 0.01f*t0);
            float t1 = a1[r2] + sh[4+r2];   z1[r2] = fmaxf(t1, 0.01f*t1);
        }
        uint4 u;
        u.x = pack2h(z0[0], z0[1]); u.y = pack2h(z0[2], z0[3]);
        u.z = pack2h(z1[0], z1[1]); u.w = pack2h(z1[2], z1[3]);
        frH[i] = __builtin_bit_cast(half8, u);
    }
}

// ---- conv2 tile MT from prefolded fragments -> LDS out staging ----
template<int MT, int P0, int NP, int NR>
__device__ __forceinline__ void conv2_tile(
    float* __restrict__ sout, const half8 (&fr0)[NR], const half8 (&fr1)[NR],
    const int col, const int g, const int lane, const char* __restrict__ ws)
{
    const uint4* wf2 = (const uint4*)(ws + WF2_OFF);
    half8 af3[6];
    #pragma unroll
    for (int hh = 0; hh < 2; ++hh)
    #pragma unroll
    for (int tap = 0; tap < 3; ++tap)
        af3[tap*2 + hh] = __builtin_bit_cast(half8, wf2[((MT*2 + hh)*3 + tap)*64 + lane]);
    float4 shv = *(const float4*)((const float*)(ws + SH2_OFF) + g*8 + MT*4);
    const float sh2[4] = {shv.x, shv.y, shv.z, shv.w};

    #pragma unroll
    for (int pp = 0; pp < NP; ++pp) {
        const int p = P0 + pp;
        f32x4 acc = {0.f,0.f,0.f,0.f};
        #pragma unroll
        for (int s = 0; s < 6; ++s) {
            const half8 bb = (s & 1) ? fr1[pp + (s >> 1)] : fr0[pp + (s >> 1)];
            acc = __builtin_amdgcn_mfma_f32_16x16x32_f16(af3[s], bb, acc, 0,0,0);
        }
        #pragma unroll
        for (int r = 0; r < 4; ++r) {
            const int oc = MT*16 + 4*g + r;
            if (oc < 20) {
                float t0 = acc[r] + sh2[r];
                t0 = fmaxf(t0, 0.01f*t0);
                sout[col*OUT_SDW + oc*11 + p] = t0;
            }
        }
    }
}

// ---- conv1 (two half-sweeps) -> fr regs -> conv2 (two tile-sweeps) -> LDS staging ----
template<int R0, int NR, int P0, int NP>
__device__ __forceinline__ void stack23(
    char* __restrict__ sxT, const int col, const int g, const int lane,
    const char* __restrict__ ws)
{
    float* sout = (float*)sxT;
    const char* yb = sxT + col * Y_BS;
    half8 fr0[NR], fr1[NR];
    conv1_half<0, R0, NR>(yb, fr0, lane, g, ws);
    __builtin_amdgcn_sched_barrier(0);    // keep the two halves' af live-ranges separate
    conv1_half<1, R0, NR>(yb, fr1, lane, g, ws);
    __syncthreads();   // all y reads done before out staging overwrites sxT
    conv2_tile<0, P0, NP, NR>(sout, fr0, fr1, col, g, lane, ws);
    __builtin_amdgcn_sched_barrier(0);
    conv2_tile<1, P0, NP, NR>(sout, fr0, fr1, col, g, lane, ws);
}

__global__ __launch_bounds__(THREADS, 2)
void peptide_v11(const float* __restrict__ x,
                 const float* __restrict__ attw,   // [15][32]
                 const float* __restrict__ attb,   // [15]
                 const char*  __restrict__ ws,     // prefolded fragments
                 float* __restrict__ out)          // [B][20][11]
{
    __shared__ __align__(16) char smem[SMEM_BYTES];
    char* sxT = smem;

    const int tid  = threadIdx.x;
    const int lane = tid & 63;
    const int wv   = tid >> 6;
    const int col  = lane & 15;
    const int g    = lane >> 4;

    // ---- gather-transpose: global x [b][c][p] -> sxT f16 [b][p][c, zero-pad to 32] ----
    {
        const float* xg = x + (size_t)blockIdx.x * (BPB * 315);
        #pragma unroll
        for (int q = 0; q < 2; ++q) {
            const int u = q * THREADS + tid;          // (b,p) task
            if (u < 240) {
                const int b = (int)(((unsigned)u * 4370u) >> 16);   // u / 15
                const int p = u - b * 15;
                const float* src = xg + b * 315 + p;
                float v[21];
                #pragma unroll
                for (int c = 0; c < 21; ++c) v[c] = src[c * 15];
                uint4 d0, d1, d2, d3;
                d0.x = pack2h(v[0],  v[1]);  d0.y = pack2h(v[2],  v[3]);
                d0.z = pack2h(v[4],  v[5]);  d0.w = pack2h(v[6],  v[7]);
                d1.x = pack2h(v[8],  v[9]);  d1.y = pack2h(v[10], v[11]);
                d1.z = pack2h(v[12], v[13]); d1.w = pack2h(v[14], v[15]);
                d2.x = pack2h(v[16], v[17]); d2.y = pack2h(v[18], v[19]);
                d2.z = pack2h(v[20], 0.f);   d2.w = 0u;
                d3.x = 0u; d3.y = 0u; d3.z = 0u; d3.w = 0u;
                char* dst = sxT + b * Y_BS + p * Y_RS;
                *(uint4*)(dst)      = d0;
                *(uint4*)(dst + 16) = d1;
                *(uint4*)(dst + 32) = d2;
                *(uint4*)(dst + 48) = d3;
            }
        }
    }

    // conv0 A-fragments from d_ws
    half8 af0[2];
    {
        const uint4* wf0 = (const uint4*)ws;
        af0[0] = __builtin_bit_cast(half8, wf0[lane]);
        af0[1] = __builtin_bit_cast(half8, wf0[64 + lane]);
    }
    __syncthreads();                      // xT ready

    // ---- conv0 MFMA + attention softmax (y in-place) ----
    if (wv == 0) conv0_att<0, 8>(sxT, af0, attw, attb, col, g, lane);
    else         conv0_att<8, 7>(sxT, af0, attw, attb, col, g, lane);
    __syncthreads();                      // y complete (cross-wave rows)

    // ---- conv1 -> regs -> conv2 -> out staging ----
    if (wv == 0) stack23<0, 8, 0, 6>(sxT, col, g, lane, ws);
    else         stack23<6, 7, 6, 5>(sxT, col, g, lane, ws);
    __syncthreads();                      // out staging complete

    // ---- gap-free coalesced copy-out: 16 x 220 dw = one 14080 B span ----
    {
        float* ob = out + (size_t)blockIdx.x * (BPB * 220);
        const float* sf = (const float*)sxT;
        #pragma unroll
        for (int j = 0; j < 7; ++j) {
            const int u = j * THREADS + tid;          // 16B unit
            if (u < 880) {
                f32x4 v = *(const f32x4*)(sf + u * 4);
                *(f32x4*)(ob + u * 4) = v;
            }
        }
    }
}

extern "C" void kernel_launch(void* const* d_in, const int* in_sizes, int n_in,
                              void* d_out, int out_size, void* d_ws, size_t ws_size,
                              hipStream_t stream) {
    const float* x    = (const float*)d_in[0];
    const float* w0   = (const float*)d_in[1];
    const float* attw = (const float*)d_in[2];
    const float* attb = (const float*)d_in[3];
    const float* w1   = (const float*)d_in[4];
    const float* cb1  = (const float*)d_in[5];
    const float* g1   = (const float*)d_in[6];
    const float* bt1  = (const float*)d_in[7];
    const float* mn1  = (const float*)d_in[8];
    const float* vr1  = (const float*)d_in[9];
    const float* w2   = (const float*)d_in[10];
    const float* cb2  = (const float*)d_in[11];
    const float* g2   = (const float*)d_in[12];
    const float* bt2  = (const float*)d_in[13];
    const float* mn2  = (const float*)d_in[14];
    const float* vr2  = (const float*)d_in[15];

    hipLaunchKernelGGL(peptide_prep, dim3(1), dim3(64), 0, stream,
                       w0, w1, cb1, g1, bt1, mn1, vr1,
                       w2, cb2, g2, bt2, mn2, vr2, (char*)d_ws);
    hipLaunchKernelGGL(peptide_v11, dim3(NBLOCKS), dim3(THREADS), 0, stream,
                       x, attw, attb, (const char*)d_ws, (float*)d_out);
}